// Round 3
// baseline (573.016 us; speedup 1.0000x reference)
//
#include <hip/hip_runtime.h>
#include <cstdint>
#include <cstddef>

#define T_STEPS 1024
#define SEG     8
#define NSEG    (T_STEPS / SEG)   // 128 segments
#define NPAIR   (NSEG / 2)        // 64 producer pairs (16 steps each)
#define NBLK    512               // 1 batch per block, 2 blocks/CU
#define LOG2E   1.4426950408889634f

typedef __attribute__((ext_vector_type(8))) _Float16 half8;
typedef __attribute__((ext_vector_type(4))) float    f32x4;
typedef __attribute__((ext_vector_type(4))) int      i32x4;

static __device__ __forceinline__ float fexp2(float x) {
#if defined(__has_builtin) && __has_builtin(__builtin_amdgcn_exp2f)
  return __builtin_amdgcn_exp2f(x);
#else
  return __exp2f(x);
#endif
}
// pre-acts arrive PRE-SCALED by log2e
static __device__ __forceinline__ float sigm2(float a) {
  return __builtin_amdgcn_rcpf(1.0f + fexp2(-a));
}
static __device__ __forceinline__ float tanhg2(float a) {
  return 2.0f * __builtin_amdgcn_rcpf(1.0f + fexp2(-(a + a))) - 1.0f;
}
static __device__ __forceinline__ float tanhc(float c) {   // tanh(c), c unscaled
  return 1.0f - 2.0f * __builtin_amdgcn_rcpf(1.0f + fexp2(c * (2.0f * LOG2E)));
}

static __device__ __forceinline__ half8 load8s(const float* s, float sc) {
  float4 a = ((const float4*)s)[0];
  float4 b = ((const float4*)s)[1];
  half8 h;
  h[0] = (_Float16)(a.x * sc); h[1] = (_Float16)(a.y * sc);
  h[2] = (_Float16)(a.z * sc); h[3] = (_Float16)(a.w * sc);
  h[4] = (_Float16)(b.x * sc); h[5] = (_Float16)(b.y * sc);
  h[6] = (_Float16)(b.z * sc); h[7] = (_Float16)(b.w * sc);
  return h;
}
// quantize 16 contiguous floats with scale s -> 16 i8 packed in 4 dwords
static __device__ __forceinline__ i32x4 quant16(const float* src, float s) {
  union { i32x4 v; signed char b[16]; } u;
  #pragma unroll
  for (int j = 0; j < 16; ++j) u.b[j] = (signed char)__float2int_rn(src[j] * s);
  return u.v;
}

// lgkm-only workgroup barrier (R8-verified): global loads float across it.
static __device__ __forceinline__ void barrier_lds() {
  __asm__ volatile("s_waitcnt lgkmcnt(0)\n\ts_barrier" ::: "memory");
}

// R19: zero-LDS recurrence chain. R18 post-mortem: step ~790cy; biggest chain
// item = h ds_write -> lgkm -> ds_read_b128 (~220cy) which exists only to
// TRANSPOSE h (lane l holds h[l]; MFMA A-frag wants lane l to hold bytes
// h[16q..16q+15]). Do it in registers (~21 VALU):
//   P1 quad_perm(1,0,3,2): pack byte pairs   P2 quad_perm(2,3,0,1): pack quads
//   P3 row_ror:4/8/12 + 12 cndmask: distribute quad-dwords across the 16-row
// (row_ror:N => out[n]=in[(n-N)&15], same convention as row_shr scan idiom).
// A-frag is now a loop-carried REGISTER; L1 still fire-and-forget writes h
// bytes to the ring for the xg2 producer (off-chain); L2 touches no LDS.
// Restructure: 1 batch/block, 4 waves, 512 blocks (2 blocks/CU -> two
// independent chains per SIMD hide producer issue):
//   w0: L1 rec seg s          w1: L2 rec seg s-3
//   w2: xg2 pair (s-2)/2 @even s (16 steps/call, M=16 frag = 16 timesteps)
//   w3: xg1 pair s/2+1  @even s (pair 0 primed pre-loop)
// Ring/buffer safety: h1ring 32 slots (w2 reads steps 16P..+15 @phase 2P+2
// while w0 writes 16P+16..+23 -> disjoint mod 32); xg pair slot = P&1 (reader
// on opposite parity of concurrent writer at every phase).
// Chain estimate: MFMA ~110 + select/cvt ~40 + act ~130 + pack ~50 = ~330cy.
__global__ __launch_bounds__(256, 2) void lstm_fused(
    const float* __restrict__ x,
    const float* __restrict__ w_ih1, const float* __restrict__ w_hh1,
    const float* __restrict__ b_ih1, const float* __restrict__ b_hh1,
    const float* __restrict__ w_ih2, const float* __restrict__ w_hh2,
    const float* __restrict__ b_ih2, const float* __restrict__ b_hh2,
    const float* __restrict__ fc1_w, const float* __restrict__ fc1_b,
    const float* __restrict__ fc2_w, const float* __restrict__ fc2_b,
    const float* __restrict__ ln_g, const float* __restrict__ ln_b,
    float* __restrict__ out)
{
  __shared__ __align__(16) signed char h1ring[32][64];   // 2 KB
  __shared__ __align__(16) float xg1b[2][16][64][4];     // 32 KB (pair dbuf)
  __shared__ __align__(16) float xg2b[2][16][64][4];     // 32 KB (pair dbuf)
  __shared__ __align__(16) float hfin[64];
  __shared__ __align__(16) float y1s[128];
  __shared__ __align__(16) float y2s[128];
  __shared__ float redmu, redrs;

  const int t   = threadIdx.x;
  const int blk = blockIdx.x;
  const int l   = t & 63;
  const int w   = t >> 6;       // 0: L1 rec, 1: L2 rec, 2: xg2 prod, 3: xg1 prod
  const int col = l & 15;
  const int q   = l >> 4;       // quad-of-16 (K-slice / k-tile select)

  const i32x4 zi = (i32x4){0, 0, 0, 0};
  f32x4 zf; zf[0] = 0.f; zf[1] = 0.f; zf[2] = 0.f; zf[3] = 0.f;

  // ---- stationary per-role weights ----
  i32x4 wq[4][4];      // w0: w_hh1 | w1: w_hh2 | w2: w_ih2 (per-row i8)
  half8 wbx[4][4];     // w3: w_ih1 f16, log2e-folded
  f32x4 fsa;           // w0/w1: this lane's unit row scales (4 gates)
  float fsx[4][4];     // w2: dequant scales
  float bL[4][4];      // w2: b2*log2e | w3: b1*log2e

  if (w < 2) {
    const float* W = w ? w_hh2 : w_hh1;
    float fsq[4][4];
    #pragma unroll
    for (int g = 0; g < 4; ++g) {
      #pragma unroll
      for (int k = 0; k < 4; ++k) {
        const int r = g * 64 + k * 16 + col;
        const float* p = W + r * 64 + q * 16;
        float m = 0.0f;
        #pragma unroll
        for (int j = 0; j < 16; ++j) m = fmaxf(m, fabsf(p[j]));
        m = fmaxf(m, __shfl_xor(m, 16, 64));
        m = fmaxf(m, __shfl_xor(m, 32, 64));
        wq[g][k] = quant16(p, 127.0f / m);
        fsq[g][k] = m * (LOG2E / 16129.0f);
      }
    }
    // lane's unit u = l = q*16+col -> fsq[g][q] via static-index selects
    #pragma unroll
    for (int g = 0; g < 4; ++g) {
      const float v01 = (q & 1) ? fsq[g][1] : fsq[g][0];
      const float v23 = (q & 1) ? fsq[g][3] : fsq[g][2];
      fsa[g] = (q & 2) ? v23 : v01;
    }
  } else if (w == 2) {
    #pragma unroll
    for (int g = 0; g < 4; ++g) {
      #pragma unroll
      for (int k = 0; k < 4; ++k) {
        const int r = g * 64 + k * 16 + col;
        const float* p = w_ih2 + r * 64 + q * 16;
        float m = 0.0f;
        #pragma unroll
        for (int j = 0; j < 16; ++j) m = fmaxf(m, fabsf(p[j]));
        m = fmaxf(m, __shfl_xor(m, 16, 64));
        m = fmaxf(m, __shfl_xor(m, 32, 64));
        wq[g][k] = quant16(p, 127.0f / m);
        fsx[g][k] = m * (LOG2E / 16129.0f);
        bL[g][k]  = (b_ih2[r] + b_hh2[r]) * LOG2E;
      }
    }
  } else {
    #pragma unroll
    for (int g = 0; g < 4; ++g) {
      #pragma unroll
      for (int k = 0; k < 4; ++k) {
        const int r = g * 64 + k * 16 + col;
        wbx[g][k] = load8s(w_ih1 + r * 32 + q * 8, LOG2E);
        bL[g][k]  = (b_ih1[r] + b_hh1[r]) * LOG2E;
      }
    }
  }

  // ---- recurrence state (loop-carried registers) ----
  float c  = 0.0f;
  i32x4 af = zi;                    // h_{t-1} i8 A-frag (replicated rows)
  const int sh1 = (l & 1) << 3;
  const int sh2 = (l & 2) << 3;
  const int jb0 = (l >> 2) & 1;     // quad index bits within 16-row
  const int jb1 = (l >> 2) & 2;

  // producer A-row mapping: row = l&15 = timestep-within-pair
  const int tl = l & 15;

  // ---- w3: xg1 pair P = log2e*(W_ih1 @ x) + b1 for 16 steps ----
  auto produce_xg1 = [&](int P) {
    const float* xs = x + ((size_t)blk * T_STEPS + (P * 16 + tl)) * 32 + q * 8;
    const float4 va = ((const float4*)xs)[0];
    const float4 vb = ((const float4*)xs)[1];
    half8 xf;
    xf[0] = (_Float16)va.x; xf[1] = (_Float16)va.y;
    xf[2] = (_Float16)va.z; xf[3] = (_Float16)va.w;
    xf[4] = (_Float16)vb.x; xf[5] = (_Float16)vb.y;
    xf[6] = (_Float16)vb.z; xf[7] = (_Float16)vb.w;
    f32x4 accf[4][4];
    #pragma unroll
    for (int g = 0; g < 4; ++g)
      #pragma unroll
      for (int k = 0; k < 4; ++k)
        accf[g][k] = __builtin_amdgcn_mfma_f32_16x16x32_f16(xf, wbx[g][k], zf, 0, 0, 0);
    float* dst = &xg1b[P & 1][0][0][0];
    #pragma unroll
    for (int k = 0; k < 4; ++k) {
      #pragma unroll
      for (int r = 0; r < 4; ++r) {
        const int row = q * 4 + r;          // timestep within pair
        f32x4 v;
        v[0] = accf[0][k][r] + bL[0][k];
        v[1] = accf[1][k][r] + bL[1][k];
        v[2] = accf[2][k][r] + bL[2][k];
        v[3] = accf[3][k][r] + bL[3][k];
        *(f32x4*)(dst + (size_t)(row * 64 + k * 16 + col) * 4) = v;
      }
    }
  };

  // ---- w2: xg2 pair P = b2 + fs*(W_ih2 @ h1) from ring, 16 steps ----
  auto produce_xg2 = [&](int P) {
    const i32x4 a = *(const i32x4*)&h1ring[(P * 16 + tl) & 31][q * 16];
    i32x4 acc[4][4];
    #pragma unroll
    for (int g = 0; g < 4; ++g)
      #pragma unroll
      for (int k = 0; k < 4; ++k)
        acc[g][k] = __builtin_amdgcn_mfma_i32_16x16x64_i8(a, wq[g][k], zi, 0, 0, 0);
    float* dst = &xg2b[P & 1][0][0][0];
    #pragma unroll
    for (int k = 0; k < 4; ++k) {
      #pragma unroll
      for (int r = 0; r < 4; ++r) {
        const int row = q * 4 + r;
        f32x4 v;
        v[0] = bL[0][k] + fsx[0][k] * (float)acc[0][k][r];
        v[1] = bL[1][k] + fsx[1][k] * (float)acc[1][k][r];
        v[2] = bL[2][k] + fsx[2][k] * (float)acc[2][k][r];
        v[3] = bL[3][k] + fsx[3][k] * (float)acc[3][k][r];
        *(f32x4*)(dst + (size_t)(row * 64 + k * 16 + col) * 4) = v;
      }
    }
  };

  // ---- recurrence: 8 steps, zero LDS on the chain ----
  auto run_seg = [&](const float* XG, int t0, bool ring, bool fin) {
    // prefetch this segment's 8 gate pre-act vectors (off-chain LDS reads)
    f32x4 xq[8];
    #pragma unroll
    for (int j = 0; j < 8; ++j)
      xq[j] = *(const f32x4*)(XG + (size_t)(j * 64 + l) * 4);
    __builtin_amdgcn_s_setprio(1);
    #pragma unroll
    for (int j8 = 0; j8 < SEG; ++j8) {
      i32x4 acc[4][4];
      #pragma unroll
      for (int g = 0; g < 4; ++g)
        #pragma unroll
        for (int k = 0; k < 4; ++k)
          acc[g][k] = __builtin_amdgcn_mfma_i32_16x16x64_i8(af, wq[g][k], zi, 0, 0, 0);
      // lane's unit u = l lives in tile k = q (static-index cndmask tree)
      float p[4];
      #pragma unroll
      for (int g = 0; g < 4; ++g) {
        const int a01 = (q & 1) ? acc[g][1][0] : acc[g][0][0];
        const int a23 = (q & 1) ? acc[g][3][0] : acc[g][2][0];
        const int ai  = (q & 2) ? a23 : a01;
        p[g] = xq[j8][g] + fsa[g] * (float)ai;
      }
      const float gi = sigm2(p[0]), gf = sigm2(p[1]);
      const float gg = tanhg2(p[2]), go = sigm2(p[3]);
      c = gf * c + gi * gg;
      const float hv = go * tanhc(c);
      const int  B  = __float2int_rn(hv * 127.0f) & 255;
      if (ring)   // off-chain byte write for the xg2 producer
        ((unsigned char*)h1ring)[((t0 + j8) & 31) * 64 + l] = (unsigned char)B;
      if (fin && j8 == SEG - 1) hfin[l] = hv;
      // in-register transpose: lane l's byte -> every lane holds h[16q..16q+15]
      const int a1 = B << sh1;
      const int t1 = __builtin_amdgcn_mov_dpp(a1, 0xB1, 0xF, 0xF, false);  // quad_perm(1,0,3,2)
      const int u  = a1 | t1;                                              // byte pair
      const int a2 = u << sh2;
      const int t2 = __builtin_amdgcn_mov_dpp(a2, 0x4E, 0xF, 0xF, false);  // quad_perm(2,3,0,1)
      const int D  = a2 | t2;                                              // quad dword
      const int e1 = __builtin_amdgcn_mov_dpp(D, 0x124, 0xF, 0xF, false);  // row_ror:4
      const int e2 = __builtin_amdgcn_mov_dpp(D, 0x128, 0xF, 0xF, false);  // row_ror:8
      const int e3 = __builtin_amdgcn_mov_dpp(D, 0x12C, 0xF, 0xF, false);  // row_ror:12
      const int e0 = D;
      // v[m] = e_{(j-m)&3}, j = quad-within-row
      const int v0 = jb1 ? (jb0 ? e3 : e2) : (jb0 ? e1 : e0);
      const int v1 = jb1 ? (jb0 ? e2 : e1) : (jb0 ? e0 : e3);
      const int v2 = jb1 ? (jb0 ? e1 : e0) : (jb0 ? e3 : e2);
      const int v3 = jb1 ? (jb0 ? e0 : e3) : (jb0 ? e2 : e1);
      af = (i32x4){v0, v1, v2, v3};
    }
    __builtin_amdgcn_s_setprio(0);
  };

  // ---- prime xg1 pair 0 ----
  if (w == 3) produce_xg1(0);
  barrier_lds();

  // ---- segmented pipeline, 131 phases ----
  for (int s = 0; s <= NSEG + 2; ++s) {
    if (w == 0) {
      if (s < NSEG)
        run_seg(&xg1b[(s >> 1) & 1][(s & 1) * 8][0][0], s * SEG, true, false);
    } else if (w == 1) {
      const int sg = s - 3;
      if (sg >= 0)
        run_seg(&xg2b[(sg >> 1) & 1][(sg & 1) * 8][0][0], sg * SEG, false,
                sg == NSEG - 1);
    } else if (w == 2) {
      if (s >= 2 && !(s & 1)) {
        const int P = (s - 2) >> 1;
        if (P < NPAIR) produce_xg2(P);
      }
    } else {
      if (!(s & 1)) {
        const int P = (s >> 1) + 1;
        if (P < NPAIR) produce_xg1(P);
      }
    }
    barrier_lds();
  }

  __syncthreads();   // full drain before epilogue

  // ---- head: y = LN(relu(hT@fc1^T+b1)@fc2^T+b2), 1 batch row ----
  if (t < 128) {
    float a = fc1_b[t];
    const float4* w4 = (const float4*)(fc1_w + t * 64);
    const float4* h4 = (const float4*)hfin;
    #pragma unroll
    for (int qq = 0; qq < 16; ++qq) {
      float4 wv = w4[qq]; float4 hv = h4[qq];
      a += wv.x * hv.x + wv.y * hv.y + wv.z * hv.z + wv.w * hv.w;
    }
    y1s[t] = fmaxf(a, 0.0f);
  }
  __syncthreads();
  if (t < 128) {
    float a = fc2_b[t];
    const float4* w4 = (const float4*)(fc2_w + t * 128);
    const float4* y4 = (const float4*)y1s;
    #pragma unroll
    for (int qq = 0; qq < 32; ++qq) {
      float4 wv = w4[qq]; float4 yv = y4[qq];
      a += wv.x * yv.x + wv.y * yv.y + wv.z * yv.z + wv.w * yv.w;
    }
    y2s[t] = a;
  }
  __syncthreads();
  if (t < 64) {
    float s_  = y2s[t] + y2s[64 + t];
    float qs  = y2s[t] * y2s[t] + y2s[64 + t] * y2s[64 + t];
    #pragma unroll
    for (int off = 32; off > 0; off >>= 1) {
      s_ += __shfl_down(s_, off, 64);
      qs += __shfl_down(qs, off, 64);
    }
    if (t == 0) {
      const float mu  = s_ * (1.0f / 128.0f);
      const float var = qs * (1.0f / 128.0f) - mu * mu;
      redmu = mu;
      redrs = rsqrtf(var + 1e-5f);
    }
  }
  __syncthreads();
  if (t < 128) {
    out[(size_t)blk * 128 + t] =
        (y2s[t] - redmu) * redrs * ln_g[t] + ln_b[t];
  }
}

extern "C" void kernel_launch(void* const* d_in, const int* in_sizes, int n_in,
                              void* d_out, int out_size, void* d_ws, size_t ws_size,
                              hipStream_t stream) {
  const float* x     = (const float*)d_in[0];
  const float* w_ih1 = (const float*)d_in[1];
  const float* w_hh1 = (const float*)d_in[2];
  const float* b_ih1 = (const float*)d_in[3];
  const float* b_hh1 = (const float*)d_in[4];
  const float* w_ih2 = (const float*)d_in[5];
  const float* w_hh2 = (const float*)d_in[6];
  const float* b_ih2 = (const float*)d_in[7];
  const float* b_hh2 = (const float*)d_in[8];
  const float* fc1_w = (const float*)d_in[9];
  const float* fc1_b = (const float*)d_in[10];
  const float* fc2_w = (const float*)d_in[11];
  const float* fc2_b = (const float*)d_in[12];
  const float* ln_g  = (const float*)d_in[13];
  const float* ln_b  = (const float*)d_in[14];
  float* out = (float*)d_out;

  lstm_fused<<<NBLK, 256, 0, stream>>>(x, w_ih1, w_hh1, b_ih1, b_hh1,
                                       w_ih2, w_hh2, b_ih2, b_hh2,
                                       fc1_w, fc1_b, fc2_w, fc2_b,
                                       ln_g, ln_b, out);
}

// Round 4
// 417.193 us; speedup vs baseline: 1.3735x; 1.3735x over previous
//
#include <hip/hip_runtime.h>
#include <cstdint>
#include <cstddef>

#define T_STEPS 1024
#define SEG     8
#define NSEG    (T_STEPS / SEG)   // 128 segments
#define NBLK    256               // 512 batch / 2 per block
#define LOG2E   1.4426950408889634f

typedef __attribute__((ext_vector_type(8))) _Float16 half8;
typedef __attribute__((ext_vector_type(4))) float    f32x4;
typedef __attribute__((ext_vector_type(4))) int      i32x4;

static __device__ __forceinline__ float fexp2(float x) {
#if defined(__has_builtin) && __has_builtin(__builtin_amdgcn_exp2f)
  return __builtin_amdgcn_exp2f(x);
#else
  return __exp2f(x);
#endif
}
// pre-acts arrive PRE-SCALED by log2e
static __device__ __forceinline__ float sigm2(float a) {
  return __builtin_amdgcn_rcpf(1.0f + fexp2(-a));
}
static __device__ __forceinline__ float tanhg2(float a) {
  return 2.0f * __builtin_amdgcn_rcpf(1.0f + fexp2(-(a + a))) - 1.0f;
}
static __device__ __forceinline__ float tanhc(float c) {   // tanh(c), c unscaled
  return 1.0f - 2.0f * __builtin_amdgcn_rcpf(1.0f + fexp2(c * (2.0f * LOG2E)));
}

static __device__ __forceinline__ half8 load8s(const float* s, float sc) {
  float4 a = ((const float4*)s)[0];
  float4 b = ((const float4*)s)[1];
  half8 h;
  h[0] = (_Float16)(a.x * sc); h[1] = (_Float16)(a.y * sc);
  h[2] = (_Float16)(a.z * sc); h[3] = (_Float16)(a.w * sc);
  h[4] = (_Float16)(b.x * sc); h[5] = (_Float16)(b.y * sc);
  h[6] = (_Float16)(b.z * sc); h[7] = (_Float16)(b.w * sc);
  return h;
}
// quantize 16 contiguous floats with scale s -> 16 i8 packed in 4 dwords
static __device__ __forceinline__ i32x4 quant16(const float* src, float s) {
  union { i32x4 v; signed char b[16]; } u;
  #pragma unroll
  for (int j = 0; j < 16; ++j) u.b[j] = (signed char)__float2int_rn(src[j] * s);
  return u.v;
}

// lgkm-only workgroup barrier (R8-verified): global loads float across it.
static __device__ __forceinline__ void barrier_lds() {
  __asm__ volatile("s_waitcnt lgkmcnt(0)\n\ts_barrier" ::: "memory");
}

// R20 = R18 structure (340us verified) + R19's DPP in-register h transpose
// (correctness-verified in R19) as the ONLY change. R19's regression was the
// confounded restructure (2 same-role chains/SIMD + phase-parity producers),
// NOT necessarily the DPP path — this round isolates it.
// Chain change: the per-step ds_write(h)->lgkm->ds_read_b128 (~150-200cy RAW,
// exists only to transpose h: lane l owns h[l], A-frag wants lane l to hold
// h[16q..16q+15]) is replaced by ~21 VALU:
//   P1 quad_perm(1,0,3,2): pack byte pairs   P2 quad_perm(2,3,0,1): pack quads
//   P3 row_ror:4/8/12 + 12 cndmask: distribute quad-dwords within the 16-row
// A-frag af is loop-carried in registers. L1 keeps the fire-and-forget ring
// byte write (off-chain; feeds xg2 producer). L2 touches no LDS on the chain.
// Per-segment xg pre-acts prefetched via 8x ds_read_b128 at phase top.
// Roles (identical to R18): w0/w1 L1 rec b0/b1 [s]; w2/w3 L2 rec b0/b1 [s-2];
// w4/w5 xg2 halves [s-1]; w6/w7 xg1 halves [s+1]. Barrier per phase (130).
// Quant scheme unchanged (per-row i8 weights, h i8 scale 127, log2e folded).
__global__ __launch_bounds__(512, 2) void lstm_fused(
    const float* __restrict__ x,
    const float* __restrict__ w_ih1, const float* __restrict__ w_hh1,
    const float* __restrict__ b_ih1, const float* __restrict__ b_hh1,
    const float* __restrict__ w_ih2, const float* __restrict__ w_hh2,
    const float* __restrict__ b_ih2, const float* __restrict__ b_hh2,
    const float* __restrict__ fc1_w, const float* __restrict__ fc1_b,
    const float* __restrict__ fc2_w, const float* __restrict__ fc2_b,
    const float* __restrict__ ln_g, const float* __restrict__ ln_b,
    float* __restrict__ out)
{
  __shared__ __align__(16) signed char h1ring[32][2][64];   // 4 KB
  __shared__ __align__(16) float xg1b[2][SEG][2][64][4];    // 32 KB (dbuf)
  __shared__ __align__(16) float xg2b[2][SEG][2][64][4];    // 32 KB (dbuf)
  __shared__ __align__(16) float hfin[2][64];
  __shared__ __align__(16) float y1s[2][128];
  __shared__ __align__(16) float y2s[2][128];
  __shared__ float redmu[2], redrs[2];

  const int t   = threadIdx.x;
  const int blk = blockIdx.x;
  const int l   = t & 63;
  const int w   = t >> 6;       // wave role 0..7
  const int col = l & 15;
  const int q   = l >> 4;       // quad (K-slice)
  const int myb = w & 1;        // recurrence waves: batch; producers: k-half
  const int kbase = (w & 1) * 2;

  // ---- zero h1 ring (h_{-1} = 0 for the xg2 producer's first reads) ----
  ((int*)h1ring)[t]       = 0;
  ((int*)h1ring)[t + 512] = 0;

  const i32x4 zi = (i32x4){0, 0, 0, 0};
  f32x4 zf; zf[0] = 0.f; zf[1] = 0.f; zf[2] = 0.f; zf[3] = 0.f;

  // ---- stationary per-role weights ----
  i32x4 wq[4][4];      // w0-3: recurrence W_hh (full)
  i32x4 wq2[4][2];     // w4/w5: W_ih2 half
  half8 wbx[4][2];     // w6/w7: W_ih1 half (f16, log2e-folded)
  f32x4 fsa;           // w0-3: this lane's unit row scales (4 gates)
  float fsx[4][2];     // w4/w5: dequant scales
  float bL[4][2];      // w4-7: log2e-scaled biases

  if (w < 4) {
    const float* W = (w < 2) ? w_hh1 : w_hh2;
    float fsq[4][4];
    #pragma unroll
    for (int g = 0; g < 4; ++g) {
      #pragma unroll
      for (int k = 0; k < 4; ++k) {
        const int r = g * 64 + k * 16 + col;       // unit u = k*16+col, gate g
        const float* p = W + r * 64 + q * 16;
        float m = 0.0f;
        #pragma unroll
        for (int j = 0; j < 16; ++j) m = fmaxf(m, fabsf(p[j]));
        m = fmaxf(m, __shfl_xor(m, 16, 64));
        m = fmaxf(m, __shfl_xor(m, 32, 64));
        wq[g][k] = quant16(p, 127.0f / m);
        fsq[g][k] = m * (LOG2E / 16129.0f);
      }
    }
    // lane's unit is u = l = q*16+col -> needs fsq[g][q] (static-index select)
    #pragma unroll
    for (int g = 0; g < 4; ++g) {
      const float v01 = (q & 1) ? fsq[g][1] : fsq[g][0];
      const float v23 = (q & 1) ? fsq[g][3] : fsq[g][2];
      fsa[g] = (q & 2) ? v23 : v01;
    }
  } else if (w < 6) {
    #pragma unroll
    for (int g = 0; g < 4; ++g) {
      #pragma unroll
      for (int k2 = 0; k2 < 2; ++k2) {
        const int r = g * 64 + (kbase + k2) * 16 + col;
        const float* p = w_ih2 + r * 64 + q * 16;
        float m = 0.0f;
        #pragma unroll
        for (int j = 0; j < 16; ++j) m = fmaxf(m, fabsf(p[j]));
        m = fmaxf(m, __shfl_xor(m, 16, 64));
        m = fmaxf(m, __shfl_xor(m, 32, 64));
        wq2[g][k2] = quant16(p, 127.0f / m);
        fsx[g][k2] = m * (LOG2E / 16129.0f);
        bL[g][k2]  = (b_ih2[r] + b_hh2[r]) * LOG2E;
      }
    }
  } else {
    #pragma unroll
    for (int g = 0; g < 4; ++g) {
      #pragma unroll
      for (int k2 = 0; k2 < 2; ++k2) {
        const int r = g * 64 + (kbase + k2) * 16 + col;
        wbx[g][k2] = load8s(w_ih1 + r * 32 + q * 8, LOG2E);
        bL[g][k2]  = (b_ih1[r] + b_hh1[r]) * LOG2E;
      }
    }
  }

  // producer A-row mapping: row = l&15 = 2*t_local + batch
  const int tl  = (l & 15) >> 1;
  const int axb = l & 1;

  // ---- recurrence state (loop-carried registers) ----
  float c  = 0.0f;
  i32x4 af = zi;                    // h_{t-1} i8 A-frag (replicated rows)
  const int sh1 = (l & 1) << 3;
  const int sh2 = (l & 2) << 3;
  const int jb0 = (l >> 2) & 1;     // quad index bits within 16-row
  const int jb1 = (l >> 2) & 2;

  // ---- w6/w7: xg1[tau] = log2e*(W_ih1 @ x) + b1 (this wave's k-half) ----
  auto produce_xg1 = [&](int tau) {
    const float* xs = x + ((size_t)(2 * blk + axb) * T_STEPS + (tau * SEG + tl)) * 32 + q * 8;
    const float4 va = ((const float4*)xs)[0];
    const float4 vb = ((const float4*)xs)[1];
    half8 xf;
    xf[0] = (_Float16)va.x; xf[1] = (_Float16)va.y;
    xf[2] = (_Float16)va.z; xf[3] = (_Float16)va.w;
    xf[4] = (_Float16)vb.x; xf[5] = (_Float16)vb.y;
    xf[6] = (_Float16)vb.z; xf[7] = (_Float16)vb.w;
    f32x4 accf[4][2];
    #pragma unroll
    for (int g = 0; g < 4; ++g)
      #pragma unroll
      for (int k2 = 0; k2 < 2; ++k2)
        accf[g][k2] = __builtin_amdgcn_mfma_f32_16x16x32_f16(xf, wbx[g][k2], zf, 0, 0, 0);
    float* dst = &xg1b[tau & 1][0][0][0][0];
    #pragma unroll
    for (int k2 = 0; k2 < 2; ++k2) {
      #pragma unroll
      for (int r = 0; r < 4; ++r) {
        const int row = q * 4 + r;          // row = 2*t_local + batch
        f32x4 v;
        v[0] = accf[0][k2][r] + bL[0][k2];
        v[1] = accf[1][k2][r] + bL[1][k2];
        v[2] = accf[2][k2][r] + bL[2][k2];
        v[3] = accf[3][k2][r] + bL[3][k2];
        *(f32x4*)(dst + (size_t)(row * 64 + (kbase + k2) * 16 + col) * 4) = v;
      }
    }
  };

  // ---- w4/w5: xg2[sg] = b2 + fs*(W_ih2 @ h1) from ring (k-half) ----
  auto produce_xg2 = [&](int sg) {
    const i32x4 a = *(const i32x4*)((const signed char*)h1ring +
                    (size_t)((((sg * SEG + tl) & 31) * 128) + axb * 64 + q * 16));
    i32x4 acc[4][2];
    #pragma unroll
    for (int g = 0; g < 4; ++g)
      #pragma unroll
      for (int k2 = 0; k2 < 2; ++k2)
        acc[g][k2] = __builtin_amdgcn_mfma_i32_16x16x64_i8(a, wq2[g][k2], zi, 0, 0, 0);
    float* dst = &xg2b[sg & 1][0][0][0][0];
    #pragma unroll
    for (int k2 = 0; k2 < 2; ++k2) {
      #pragma unroll
      for (int r = 0; r < 4; ++r) {
        const int row = q * 4 + r;
        f32x4 v;
        v[0] = bL[0][k2] + fsx[0][k2] * (float)acc[0][k2][r];
        v[1] = bL[1][k2] + fsx[1][k2] * (float)acc[1][k2][r];
        v[2] = bL[2][k2] + fsx[2][k2] * (float)acc[2][k2][r];
        v[3] = bL[3][k2] + fsx[3][k2] * (float)acc[3][k2][r];
        *(f32x4*)(dst + (size_t)(row * 64 + (kbase + k2) * 16 + col) * 4) = v;
      }
    }
  };

  // ---- recurrence: 8 steps, zero LDS on the chain (DPP h transpose) ----
  auto run_seg = [&](const float* XG, int t0, bool ring, bool fin) {
    // prefetch this segment's 8 gate pre-act vectors (off-chain LDS reads)
    f32x4 xq[8];
    #pragma unroll
    for (int j = 0; j < 8; ++j)
      xq[j] = *(const f32x4*)(XG + (size_t)((j * 2 + myb) * 64 + l) * 4);
    __builtin_amdgcn_s_setprio(1);
    #pragma unroll
    for (int j8 = 0; j8 < SEG; ++j8) {
      i32x4 acc[4][4];
      #pragma unroll
      for (int g = 0; g < 4; ++g)
        #pragma unroll
        for (int k = 0; k < 4; ++k)
          acc[g][k] = __builtin_amdgcn_mfma_i32_16x16x64_i8(af, wq[g][k], zi, 0, 0, 0);
      // lane's unit u = l lives in tile k = q (static-index cndmask tree)
      float p[4];
      #pragma unroll
      for (int g = 0; g < 4; ++g) {
        const int a01 = (q & 1) ? acc[g][1][0] : acc[g][0][0];
        const int a23 = (q & 1) ? acc[g][3][0] : acc[g][2][0];
        const int ai  = (q & 2) ? a23 : a01;
        p[g] = xq[j8][g] + fsa[g] * (float)ai;
      }
      const float gi = sigm2(p[0]), gf = sigm2(p[1]);
      const float gg = tanhg2(p[2]), go = sigm2(p[3]);
      c = gf * c + gi * gg;
      const float hv = go * tanhc(c);
      const int  B  = __float2int_rn(hv * 127.0f) & 255;
      if (ring)   // off-chain byte write for the xg2 producer
        ((signed char*)h1ring)[((t0 + j8) & 31) * 128 + myb * 64 + l] = (signed char)B;
      if (fin && j8 == SEG - 1) hfin[myb][l] = hv;
      // in-register transpose: lane l's byte -> every lane holds h[16q..16q+15]
      const int a1 = B << sh1;
      const int t1 = __builtin_amdgcn_mov_dpp(a1, 0xB1, 0xF, 0xF, false);  // quad_perm(1,0,3,2)
      const int u  = a1 | t1;                                              // byte pair
      const int a2 = u << sh2;
      const int t2 = __builtin_amdgcn_mov_dpp(a2, 0x4E, 0xF, 0xF, false);  // quad_perm(2,3,0,1)
      const int D  = a2 | t2;                                              // quad dword
      const int e1 = __builtin_amdgcn_mov_dpp(D, 0x124, 0xF, 0xF, false);  // row_ror:4
      const int e2 = __builtin_amdgcn_mov_dpp(D, 0x128, 0xF, 0xF, false);  // row_ror:8
      const int e3 = __builtin_amdgcn_mov_dpp(D, 0x12C, 0xF, 0xF, false);  // row_ror:12
      const int e0 = D;
      // af[m] = e_{(j-m)&3}, j = quad-within-row
      const int v0 = jb1 ? (jb0 ? e3 : e2) : (jb0 ? e1 : e0);
      const int v1 = jb1 ? (jb0 ? e2 : e1) : (jb0 ? e0 : e3);
      const int v2 = jb1 ? (jb0 ? e1 : e0) : (jb0 ? e3 : e2);
      const int v3 = jb1 ? (jb0 ? e0 : e3) : (jb0 ? e2 : e1);
      af = (i32x4){v0, v1, v2, v3};
    }
    __builtin_amdgcn_s_setprio(0);
  };

  // ---- prime xg1 for segment 0 (ring zero-writes also drain here) ----
  if (w >= 6) produce_xg1(0);
  barrier_lds();

  // ---- segmented pipeline (identical skew to R18) ----
  for (int s = 0; s <= NSEG + 1; ++s) {
    if (w < 2) {
      if (s < NSEG)
        run_seg(&xg1b[s & 1][0][0][0][0], s * SEG, true, false);
    } else if (w < 4) {
      const int sg = s - 2;
      if (sg >= 0)
        run_seg(&xg2b[sg & 1][0][0][0][0], sg * SEG, false, sg == NSEG - 1);
    } else if (w < 6) {
      const int sg = s - 1;
      if (sg >= 0 && sg < NSEG) produce_xg2(sg);
    } else {
      if (s + 1 < NSEG) produce_xg1(s + 1);
    }
    barrier_lds();
  }

  __syncthreads();   // full drain before epilogue

  // ---- head: y = LN(relu(hT@fc1^T+b1)@fc2^T+b2), 2 batch rows ----
  if (t < 256) {
    const int bi = t >> 7, j = t & 127;
    float accv = fc1_b[j];
    const float4* w4 = (const float4*)(fc1_w + j * 64);
    const float4* h4 = (const float4*)hfin[bi];
    #pragma unroll
    for (int qq = 0; qq < 16; ++qq) {
      float4 wv = w4[qq]; float4 hv = h4[qq];
      accv += wv.x * hv.x + wv.y * hv.y + wv.z * hv.z + wv.w * hv.w;
    }
    y1s[bi][j] = fmaxf(accv, 0.0f);
  }
  __syncthreads();
  if (t < 256) {
    const int bi = t >> 7, j = t & 127;
    float accv = fc2_b[j];
    const float4* w4 = (const float4*)(fc2_w + j * 128);
    const float4* y4 = (const float4*)y1s[bi];
    #pragma unroll
    for (int qq = 0; qq < 32; ++qq) {
      float4 wv = w4[qq]; float4 yv = y4[qq];
      accv += wv.x * yv.x + wv.y * yv.y + wv.z * yv.z + wv.w * yv.w;
    }
    y2s[bi][j] = accv;
  }
  __syncthreads();
  if (t < 128) {
    const int bi = t >> 6, jj = t & 63;
    float s  = y2s[bi][jj] + y2s[bi][64 + jj];
    float qs = y2s[bi][jj] * y2s[bi][jj] + y2s[bi][64 + jj] * y2s[bi][64 + jj];
    #pragma unroll
    for (int off = 32; off > 0; off >>= 1) {
      s  += __shfl_down(s, off, 64);
      qs += __shfl_down(qs, off, 64);
    }
    if (jj == 0) {
      const float mu  = s * (1.0f / 128.0f);
      const float var = qs * (1.0f / 128.0f) - mu * mu;
      redmu[bi] = mu;
      redrs[bi] = rsqrtf(var + 1e-5f);
    }
  }
  __syncthreads();
  if (t < 256) {
    const int bi = t >> 7, j = t & 127;
    out[(size_t)(2 * blk + bi) * 128 + j] =
        (y2s[bi][j] - redmu[bi]) * redrs[bi] * ln_g[j] + ln_b[j];
  }
}

extern "C" void kernel_launch(void* const* d_in, const int* in_sizes, int n_in,
                              void* d_out, int out_size, void* d_ws, size_t ws_size,
                              hipStream_t stream) {
  const float* x     = (const float*)d_in[0];
  const float* w_ih1 = (const float*)d_in[1];
  const float* w_hh1 = (const float*)d_in[2];
  const float* b_ih1 = (const float*)d_in[3];
  const float* b_hh1 = (const float*)d_in[4];
  const float* w_ih2 = (const float*)d_in[5];
  const float* w_hh2 = (const float*)d_in[6];
  const float* b_ih2 = (const float*)d_in[7];
  const float* b_hh2 = (const float*)d_in[8];
  const float* fc1_w = (const float*)d_in[9];
  const float* fc1_b = (const float*)d_in[10];
  const float* fc2_w = (const float*)d_in[11];
  const float* fc2_b = (const float*)d_in[12];
  const float* ln_g  = (const float*)d_in[13];
  const float* ln_b  = (const float*)d_in[14];
  float* out = (float*)d_out;

  lstm_fused<<<NBLK, 512, 0, stream>>>(x, w_ih1, w_hh1, b_ih1, b_hh1,
                                       w_ih2, w_hh2, b_ih2, b_hh2,
                                       fc1_w, fc1_b, fc2_w, fc2_b,
                                       ln_g, ln_b, out);
}

// Round 6
// 409.111 us; speedup vs baseline: 1.4006x; 1.0198x over previous
//
#include <hip/hip_runtime.h>
#include <cstdint>
#include <cstddef>

#define T_STEPS 1024
#define SEG     16
#define NSEG    (T_STEPS / SEG)   // 64 segments
#define NBLK    256               // 512 batch / 2 per block
#define LOG2E   1.4426950408889634f

typedef __attribute__((ext_vector_type(8))) _Float16 half8;
typedef __attribute__((ext_vector_type(4))) float    f32x4;
typedef __attribute__((ext_vector_type(4))) int      i32x4;

static __device__ __forceinline__ float fexp2(float x) {
#if defined(__has_builtin) && __has_builtin(__builtin_amdgcn_exp2f)
  return __builtin_amdgcn_exp2f(x);
#else
  return __exp2f(x);
#endif
}
// pre-acts arrive PRE-SCALED by log2e
static __device__ __forceinline__ float sigm2(float a) {
  return __builtin_amdgcn_rcpf(1.0f + fexp2(-a));
}
static __device__ __forceinline__ float tanhg2(float a) {
  return 2.0f * __builtin_amdgcn_rcpf(1.0f + fexp2(-(a + a))) - 1.0f;
}
// 127*tanh(c), c unscaled (127 quant scale folded into the constant)
static __device__ __forceinline__ float tanhc127(float c) {
  return 127.0f - 254.0f * __builtin_amdgcn_rcpf(1.0f + fexp2(c * (2.0f * LOG2E)));
}

static __device__ __forceinline__ half8 load8s(const float* s, float sc) {
  float4 a = ((const float4*)s)[0];
  float4 b = ((const float4*)s)[1];
  half8 h;
  h[0] = (_Float16)(a.x * sc); h[1] = (_Float16)(a.y * sc);
  h[2] = (_Float16)(a.z * sc); h[3] = (_Float16)(a.w * sc);
  h[4] = (_Float16)(b.x * sc); h[5] = (_Float16)(b.y * sc);
  h[6] = (_Float16)(b.z * sc); h[7] = (_Float16)(b.w * sc);
  return h;
}
// quantize 16 contiguous floats with scale s -> 16 i8 packed in 4 dwords
static __device__ __forceinline__ i32x4 quant16(const float* src, float s) {
  union { i32x4 v; signed char b[16]; } u;
  #pragma unroll
  for (int j = 0; j < 16; ++j) u.b[j] = (signed char)__float2int_rn(src[j] * s);
  return u.v;
}

// lgkm-only workgroup barrier (R8-verified): global loads float across it.
static __device__ __forceinline__ void barrier_lds() {
  __asm__ volatile("s_waitcnt lgkmcnt(0)\n\ts_barrier" ::: "memory");
}

// R22 = R21 resubmit (R5 bench was an infra failure: "container failed twice";
// kernel audit found no hang path: uniform barriers, LDS 134.7KB<160KB, no
// data-dependent loops). Experiment: R18 (340us best) with SEG 8->16.
// Rationale: R20 isolated the h-exchange (DPP 356 vs LDS 340) -> not the
// lever. Bottom-up chain estimate (~400cy) undershoots measured ~800cy/step
// by 2x; hypothesis: ~3000cy per-PHASE overhead (8-wave barrier arrival
// jitter + xq-prefetch head wait + producer skew) amortized over only 8
// steps. SEG=16 halves phase count (130->66):
//  - xg dbufs double to 64KB each; LDS ~135KB, still 1 block/CU (grid=CUs).
//  - producers run 2 MFMA passes per phase (A-frag M=16 = 8 steps x 2 batch).
//  - xq prefetch: rolling refill — step j8<8 consumes xq[j8] then reloads it
//    with the j8+8 value (0 extra VGPRs, 8 steps of latency cover each).
//  - chain micro-opt: 127 folded into tanh constant (one fewer dependent mul).
// Roles (R18): w0/w1 L1 rec b0/b1 [s]; w2/w3 L2 rec b0/b1 [s-2];
// w4/w5 xg2 halves [s-1]; w6/w7 xg1 halves [s+1]. lgkm-only barrier per phase.
// Ring safety: w0 writes slots [16s,16s+16) mod 32 while w4/w5 read
// [16s-16,16s) mod 32 -> disjoint. xg dbuf parity: producer writes (s+1)&1 /
// (s-1)&1 opposite to concurrent reader at every phase (same proof as R18).
// Quant scheme unchanged (per-row i8 weights, h i8 scale 127, log2e folded).
__global__ __launch_bounds__(512, 2) void lstm_fused(
    const float* __restrict__ x,
    const float* __restrict__ w_ih1, const float* __restrict__ w_hh1,
    const float* __restrict__ b_ih1, const float* __restrict__ b_hh1,
    const float* __restrict__ w_ih2, const float* __restrict__ w_hh2,
    const float* __restrict__ b_ih2, const float* __restrict__ b_hh2,
    const float* __restrict__ fc1_w, const float* __restrict__ fc1_b,
    const float* __restrict__ fc2_w, const float* __restrict__ fc2_b,
    const float* __restrict__ ln_g, const float* __restrict__ ln_b,
    float* __restrict__ out)
{
  __shared__ __align__(16) signed char h1ring[32][2][64];   // 4 KB
  __shared__ __align__(16) signed char h2ring[2][2][64];    // 256 B
  __shared__ __align__(16) float xg1b[2][SEG][2][64][4];    // 64 KB (dbuf)
  __shared__ __align__(16) float xg2b[2][SEG][2][64][4];    // 64 KB (dbuf)
  __shared__ __align__(16) float hfin[2][64];
  __shared__ __align__(16) float y1s[2][128];
  __shared__ __align__(16) float y2s[2][128];
  __shared__ float redmu[2], redrs[2];

  const int t   = threadIdx.x;
  const int blk = blockIdx.x;
  const int l   = t & 63;
  const int w   = t >> 6;       // wave role 0..7
  const int col = l & 15;
  const int q   = l >> 4;       // quad (K-slice)
  const int myb = w & 1;        // recurrence waves: batch; producers: k-half
  const int kbase = (w & 1) * 2;

  // ---- zero h rings (h_{-1} = 0) ----
  ((int*)h1ring)[t]       = 0;
  ((int*)h1ring)[t + 512] = 0;
  if (t < 64) ((int*)h2ring)[t] = 0;

  const i32x4 zi = (i32x4){0, 0, 0, 0};
  f32x4 zf; zf[0] = 0.f; zf[1] = 0.f; zf[2] = 0.f; zf[3] = 0.f;

  // ---- stationary per-role weights ----
  i32x4 wq[4][4];      // w0-3: recurrence W_hh (full)
  i32x4 wq2[4][2];     // w4/w5: W_ih2 half
  half8 wbx[4][2];     // w6/w7: W_ih1 half (f16, log2e-folded)
  f32x4 fsa;           // w0-3: this lane's unit row scales (4 gates)
  float fsx[4][2];     // w4/w5: dequant scales
  float bL[4][2];      // w4-7: log2e-scaled biases

  if (w < 4) {
    const float* W = (w < 2) ? w_hh1 : w_hh2;
    float fsq[4][4];
    #pragma unroll
    for (int g = 0; g < 4; ++g) {
      #pragma unroll
      for (int k = 0; k < 4; ++k) {
        const int r = g * 64 + k * 16 + col;       // unit u = k*16+col, gate g
        const float* p = W + r * 64 + q * 16;
        float m = 0.0f;
        #pragma unroll
        for (int j = 0; j < 16; ++j) m = fmaxf(m, fabsf(p[j]));
        m = fmaxf(m, __shfl_xor(m, 16, 64));
        m = fmaxf(m, __shfl_xor(m, 32, 64));
        wq[g][k] = quant16(p, 127.0f / m);
        fsq[g][k] = m * (LOG2E / 16129.0f);
      }
    }
    // lane's unit is u = l = q*16+col -> needs fsq[g][q] (static-index select)
    #pragma unroll
    for (int g = 0; g < 4; ++g) {
      const float v01 = (q & 1) ? fsq[g][1] : fsq[g][0];
      const float v23 = (q & 1) ? fsq[g][3] : fsq[g][2];
      fsa[g] = (q & 2) ? v23 : v01;
    }
  } else if (w < 6) {
    #pragma unroll
    for (int g = 0; g < 4; ++g) {
      #pragma unroll
      for (int k2 = 0; k2 < 2; ++k2) {
        const int r = g * 64 + (kbase + k2) * 16 + col;
        const float* p = w_ih2 + r * 64 + q * 16;
        float m = 0.0f;
        #pragma unroll
        for (int j = 0; j < 16; ++j) m = fmaxf(m, fabsf(p[j]));
        m = fmaxf(m, __shfl_xor(m, 16, 64));
        m = fmaxf(m, __shfl_xor(m, 32, 64));
        wq2[g][k2] = quant16(p, 127.0f / m);
        fsx[g][k2] = m * (LOG2E / 16129.0f);
        bL[g][k2]  = (b_ih2[r] + b_hh2[r]) * LOG2E;
      }
    }
  } else {
    #pragma unroll
    for (int g = 0; g < 4; ++g) {
      #pragma unroll
      for (int k2 = 0; k2 < 2; ++k2) {
        const int r = g * 64 + (kbase + k2) * 16 + col;
        wbx[g][k2] = load8s(w_ih1 + r * 32 + q * 8, LOG2E);
        bL[g][k2]  = (b_ih1[r] + b_hh1[r]) * LOG2E;
      }
    }
  }

  // producer A-row mapping: row = l&15 = 2*t_local + batch
  const int tl  = (l & 15) >> 1;
  const int axb = l & 1;

  float c = 0.0f;

  // ---- w6/w7: xg1[tau] = log2e*(W_ih1 @ x) + b1 (k-half, 2 passes of 8t) ----
  auto produce_xg1 = [&](int tau) {
    float* dst = &xg1b[tau & 1][0][0][0][0];
    #pragma unroll
    for (int h8 = 0; h8 < 2; ++h8) {
      const float* xs = x + ((size_t)(2 * blk + axb) * T_STEPS +
                             (tau * SEG + h8 * 8 + tl)) * 32 + q * 8;
      const float4 va = ((const float4*)xs)[0];
      const float4 vb = ((const float4*)xs)[1];
      half8 xf;
      xf[0] = (_Float16)va.x; xf[1] = (_Float16)va.y;
      xf[2] = (_Float16)va.z; xf[3] = (_Float16)va.w;
      xf[4] = (_Float16)vb.x; xf[5] = (_Float16)vb.y;
      xf[6] = (_Float16)vb.z; xf[7] = (_Float16)vb.w;
      f32x4 accf[4][2];
      #pragma unroll
      for (int g = 0; g < 4; ++g)
        #pragma unroll
        for (int k2 = 0; k2 < 2; ++k2)
          accf[g][k2] = __builtin_amdgcn_mfma_f32_16x16x32_f16(xf, wbx[g][k2], zf, 0, 0, 0);
      #pragma unroll
      for (int k2 = 0; k2 < 2; ++k2) {
        #pragma unroll
        for (int r = 0; r < 4; ++r) {
          const int row = h8 * 16 + q * 4 + r;   // row = 2*t_local + batch
          f32x4 v;
          v[0] = accf[0][k2][r] + bL[0][k2];
          v[1] = accf[1][k2][r] + bL[1][k2];
          v[2] = accf[2][k2][r] + bL[2][k2];
          v[3] = accf[3][k2][r] + bL[3][k2];
          *(f32x4*)(dst + (size_t)(row * 64 + (kbase + k2) * 16 + col) * 4) = v;
        }
      }
    }
  };

  // ---- w4/w5: xg2[sg] = b2 + fs*(W_ih2 @ h1) from ring (k-half, 2 passes) ----
  auto produce_xg2 = [&](int sg) {
    float* dst = &xg2b[sg & 1][0][0][0][0];
    #pragma unroll
    for (int h8 = 0; h8 < 2; ++h8) {
      const i32x4 a = *(const i32x4*)((const signed char*)h1ring +
                      (size_t)((((sg * SEG + h8 * 8 + tl) & 31) * 128) + axb * 64 + q * 16));
      i32x4 acc[4][2];
      #pragma unroll
      for (int g = 0; g < 4; ++g)
        #pragma unroll
        for (int k2 = 0; k2 < 2; ++k2)
          acc[g][k2] = __builtin_amdgcn_mfma_i32_16x16x64_i8(a, wq2[g][k2], zi, 0, 0, 0);
      #pragma unroll
      for (int k2 = 0; k2 < 2; ++k2) {
        #pragma unroll
        for (int r = 0; r < 4; ++r) {
          const int row = h8 * 16 + q * 4 + r;
          f32x4 v;
          v[0] = bL[0][k2] + fsx[0][k2] * (float)acc[0][k2][r];
          v[1] = bL[1][k2] + fsx[1][k2] * (float)acc[1][k2][r];
          v[2] = bL[2][k2] + fsx[2][k2] * (float)acc[2][k2][r];
          v[3] = bL[3][k2] + fsx[3][k2] * (float)acc[3][k2][r];
          *(f32x4*)(dst + (size_t)(row * 64 + (kbase + k2) * 16 + col) * 4) = v;
        }
      }
    }
  };

  // ---- recurrence: 16 steps, one batch, one unit per lane, barrier-free ----
  auto run_seg = [&](const float* XG, signed char* RING, int RM, int t0, bool fin) {
    // rolling xq prefetch: 8 in flight; step j8<8 consumes xq[j8] then
    // reloads it with the step j8+8 value (8 steps of latency cover).
    f32x4 xq[8];
    #pragma unroll
    for (int j = 0; j < 8; ++j)
      xq[j] = *(const f32x4*)(XG + (size_t)((j * 2 + myb) * 64 + l) * 4);
    __builtin_amdgcn_s_setprio(1);
    #pragma unroll
    for (int j8 = 0; j8 < SEG; ++j8) {
      const int tt = t0 + j8;
      // previous h, replicated M: all lanes in a q-group read the same 16B
      const i32x4 a = *(const i32x4*)(RING + ((tt - 1) & RM) * 128 + myb * 64 + q * 16);
      const f32x4 xv = xq[j8 & 7];
      if (j8 < 8)
        xq[j8 & 7] = *(const f32x4*)(XG + (size_t)(((j8 + 8) * 2 + myb) * 64 + l) * 4);
      i32x4 acc[4][4];
      #pragma unroll
      for (int g = 0; g < 4; ++g)
        #pragma unroll
        for (int k = 0; k < 4; ++k)
          acc[g][k] = __builtin_amdgcn_mfma_i32_16x16x64_i8(a, wq[g][k], zi, 0, 0, 0);
      // lane's unit u = l lives in tile k = q (static-index cndmask tree)
      float p[4];
      #pragma unroll
      for (int g = 0; g < 4; ++g) {
        const int a01 = (q & 1) ? acc[g][1][0] : acc[g][0][0];
        const int a23 = (q & 1) ? acc[g][3][0] : acc[g][2][0];
        const int ai  = (q & 2) ? a23 : a01;
        p[g] = xv[g] + fsa[g] * (float)ai;
      }
      const float gi = sigm2(p[0]), gf = sigm2(p[1]);
      const float gg = tanhg2(p[2]), go = sigm2(p[3]);
      c = gf * c + gi * gg;
      const float hq = go * tanhc127(c);       // = 127 * h
      RING[(tt & RM) * 128 + myb * 64 + l] = (signed char)__float2int_rn(hq);
      if (fin && j8 == SEG - 1) hfin[myb][l] = hq * (1.0f / 127.0f);
    }
    __builtin_amdgcn_s_setprio(0);
  };

  // ---- prime xg1 for segment 0 (ring zero-writes also drain here) ----
  if (w >= 6) produce_xg1(0);
  barrier_lds();

  // ---- segmented pipeline, 66 phases ----
  for (int s = 0; s <= NSEG + 1; ++s) {
    if (w < 2) {
      if (s < NSEG)
        run_seg(&xg1b[s & 1][0][0][0][0], (signed char*)h1ring, 31, s * SEG, false);
    } else if (w < 4) {
      const int sg = s - 2;
      if (sg >= 0)
        run_seg(&xg2b[sg & 1][0][0][0][0], (signed char*)h2ring, 1, sg * SEG,
                sg == NSEG - 1);
    } else if (w < 6) {
      const int sg = s - 1;
      if (sg >= 0 && sg < NSEG) produce_xg2(sg);
    } else {
      if (s + 1 < NSEG) produce_xg1(s + 1);
    }
    barrier_lds();
  }

  __syncthreads();   // full drain before epilogue

  // ---- head: y = LN(relu(hT@fc1^T+b1)@fc2^T+b2), 2 batch rows ----
  if (t < 256) {
    const int bi = t >> 7, j = t & 127;
    float accv = fc1_b[j];
    const float4* w4 = (const float4*)(fc1_w + j * 64);
    const float4* h4 = (const float4*)hfin[bi];
    #pragma unroll
    for (int qq = 0; qq < 16; ++qq) {
      float4 wv = w4[qq]; float4 hv = h4[qq];
      accv += wv.x * hv.x + wv.y * hv.y + wv.z * hv.z + wv.w * hv.w;
    }
    y1s[bi][j] = fmaxf(accv, 0.0f);
  }
  __syncthreads();
  if (t < 256) {
    const int bi = t >> 7, j = t & 127;
    float accv = fc2_b[j];
    const float4* w4 = (const float4*)(fc2_w + j * 128);
    const float4* y4 = (const float4*)y1s[bi];
    #pragma unroll
    for (int qq = 0; qq < 32; ++qq) {
      float4 wv = w4[qq]; float4 yv = y4[qq];
      accv += wv.x * yv.x + wv.y * yv.y + wv.z * yv.z + wv.w * yv.w;
    }
    y2s[bi][j] = accv;
  }
  __syncthreads();
  if (t < 128) {
    const int bi = t >> 6, jj = t & 63;
    float s  = y2s[bi][jj] + y2s[bi][64 + jj];
    float qs = y2s[bi][jj] * y2s[bi][jj] + y2s[bi][64 + jj] * y2s[bi][64 + jj];
    #pragma unroll
    for (int off = 32; off > 0; off >>= 1) {
      s  += __shfl_down(s, off, 64);
      qs += __shfl_down(qs, off, 64);
    }
    if (jj == 0) {
      const float mu  = s * (1.0f / 128.0f);
      const float var = qs * (1.0f / 128.0f) - mu * mu;
      redmu[bi] = mu;
      redrs[bi] = rsqrtf(var + 1e-5f);
    }
  }
  __syncthreads();
  if (t < 256) {
    const int bi = t >> 7, j = t & 127;
    out[(size_t)(2 * blk + bi) * 128 + j] =
        (y2s[bi][j] - redmu[bi]) * redrs[bi] * ln_g[j] + ln_b[j];
  }
}

extern "C" void kernel_launch(void* const* d_in, const int* in_sizes, int n_in,
                              void* d_out, int out_size, void* d_ws, size_t ws_size,
                              hipStream_t stream) {
  const float* x     = (const float*)d_in[0];
  const float* w_ih1 = (const float*)d_in[1];
  const float* w_hh1 = (const float*)d_in[2];
  const float* b_ih1 = (const float*)d_in[3];
  const float* b_hh1 = (const float*)d_in[4];
  const float* w_ih2 = (const float*)d_in[5];
  const float* w_hh2 = (const float*)d_in[6];
  const float* b_ih2 = (const float*)d_in[7];
  const float* b_hh2 = (const float*)d_in[8];
  const float* fc1_w = (const float*)d_in[9];
  const float* fc1_b = (const float*)d_in[10];
  const float* fc2_w = (const float*)d_in[11];
  const float* fc2_b = (const float*)d_in[12];
  const float* ln_g  = (const float*)d_in[13];
  const float* ln_b  = (const float*)d_in[14];
  float* out = (float*)d_out;

  lstm_fused<<<NBLK, 512, 0, stream>>>(x, w_ih1, w_hh1, b_ih1, b_hh1,
                                       w_ih2, w_hh2, b_ih2, b_hh2,
                                       fc1_w, fc1_b, fc2_w, fc2_b,
                                       ln_g, ln_b, out);
}